// Round 9
// baseline (140.204 us; speedup 1.0000x reference)
//
#include <hip/hip_runtime.h>

#define D 256
#define S 2048
#define B 8
#define DSQ (D * D)   // 65536
#define INV3 (1.0f / 2043.0f)   // 1/(S-5)
#define MAGIC 0x5CA1AB1Eu

typedef __bf16 bf16x8 __attribute__((ext_vector_type(8)));
typedef float f32x4 __attribute__((ext_vector_type(4)));

__device__ __forceinline__ unsigned short f2bf(float f) {
    union { float f; unsigned int u; } v; v.f = f;
    unsigned int u = v.u;
    u += 0x7fffu + ((u >> 16) & 1u);   // RTNE
    return (unsigned short)(u >> 16);
}

__device__ __forceinline__ void gl2lds16(const void* g, void* l) {
    __builtin_amdgcn_global_load_lds(
        (const __attribute__((address_space(1))) void*)g,
        (__attribute__((address_space(3))) void*)l, 16, 0, 0);
}

// ---------------- K1: prep (512 worker blocks) + Tb/boundary (40 spin blocks)
// Workers: bf16-cast 32 rows of x -> xh, channel sums -> atomicAdd total,
// blocks<160 also build Cbs; release flags[blk] when done.
// Blocks 512..519: Tb[b]; 520..551: boundary rows — spin on b's 64 flags.
// total[] starts at ws-poison 0xAAAAAAAA = -3.03e-13 per element: negligible.
__global__ __launch_bounds__(256) void k_prep(const float* __restrict__ x,
                                              const float* __restrict__ comp,
                                              const float* __restrict__ basis,
                                              const float* __restrict__ root,
                                              const float* __restrict__ bias,
                                              unsigned short* __restrict__ xh,
                                              float* __restrict__ total,
                                              unsigned int* __restrict__ flags,
                                              unsigned short* __restrict__ Cbs,
                                              float* __restrict__ Tb,
                                              float* __restrict__ out) {
    const int blk = blockIdx.x;
    const int tid = threadIdx.x;

    if (blk < 512) {   // ---------------- worker ----------------
        int b = blk >> 6, chunk = blk & 63;
        __shared__ float ps[4][D];
        int rg = tid >> 6;               // 0..3 row-group (8 rows each)
        int c4 = (tid & 63) << 2;
        int row0 = chunk * 32 + rg * 8;
        const float4* xb = (const float4*)(x + ((size_t)b * S + row0) * D + c4);
        ushort4* dst = (ushort4*)(xh + ((size_t)(1 + b * S + row0)) * D + c4);
        float4 s = {0.f, 0.f, 0.f, 0.f};
        #pragma unroll
        for (int i = 0; i < 8; ++i) {
            float4 v = xb[(size_t)i * 64];
            ushort4 o;
            o.x = f2bf(v.x); o.y = f2bf(v.y); o.z = f2bf(v.z); o.w = f2bf(v.w);
            dst[(size_t)i * 64] = o;
            s.x += v.x; s.y += v.y; s.z += v.z; s.w += v.w;
        }
        *(float4*)&ps[rg][c4] = s;

        if (blk < 160) {                 // Cbs[step][n][32] bf16
            int step = blk >> 2, q = blk & 3;
            int ji = step >> 3, kc = step & 7;
            int n = tid;
            float a0 = (ji == 2) ? 1.f : 0.f;
            float a1 = (ji == 1 || ji == 3) ? 0.5f : 0.f;
            float a2 = (ji == 0 || ji == 4) ? 0.5f : 0.f;
            float ar = (ji == 1) ? 1.f : 0.f;
            float cb0 = a0 * comp[0] + a1 * comp[2] + a2 * comp[4] - INV3 * comp[6];
            float cb1 = a0 * comp[1] + a1 * comp[3] + a2 * comp[5] - INV3 * comp[7];
            unsigned short buf[8];
            #pragma unroll
            for (int kk = 0; kk < 8; ++kk) {
                int i = kc * 32 + q * 8 + kk;
                buf[kk] = f2bf(cb0 * basis[i * D + n] + cb1 * basis[DSQ + i * D + n]
                               + ar * root[i * D + n]);
            }
            *(uint4*)(Cbs + ((size_t)step * 256 + n) * 32 + q * 8) = *(uint4*)buf;
        }
        __syncthreads();
        if (tid < 64) {
            float4 s4;
            s4.x = ps[0][tid*4+0] + ps[1][tid*4+0] + ps[2][tid*4+0] + ps[3][tid*4+0];
            s4.y = ps[0][tid*4+1] + ps[1][tid*4+1] + ps[2][tid*4+1] + ps[3][tid*4+1];
            s4.z = ps[0][tid*4+2] + ps[1][tid*4+2] + ps[2][tid*4+2] + ps[3][tid*4+2];
            s4.w = ps[0][tid*4+3] + ps[1][tid*4+3] + ps[2][tid*4+3] + ps[3][tid*4+3];
            int base = b * D + tid * 4;
            atomicAdd(&total[base + 0], s4.x);
            atomicAdd(&total[base + 1], s4.y);
            atomicAdd(&total[base + 2], s4.z);
            atomicAdd(&total[base + 3], s4.w);
            __threadfence();
        }
        __syncthreads();
        if (tid == 0)
            __hip_atomic_store(&flags[blk], MAGIC, __ATOMIC_RELEASE,
                               __HIP_MEMORY_SCOPE_AGENT);
        return;
    }

    // ---------------- spin blocks ----------------
    const int r  = blk - 512;
    const int b  = (r < 8) ? r : ((r - 8) >> 2);
    // wait for this b's 64 worker chunks
    if (tid < 64) {
        unsigned int* f = &flags[b * 64 + tid];
        while (__hip_atomic_load(f, __ATOMIC_ACQUIRE, __HIP_MEMORY_SCOPE_AGENT)
               != MAGIC) { __builtin_amdgcn_s_sleep(1); }
    }
    __syncthreads();

    __shared__ float tot[D];
    tot[tid] = __hip_atomic_load(&total[b * D + tid], __ATOMIC_RELAXED,
                                 __HIP_MEMORY_SCOPE_AGENT);
    __syncthreads();

    if (r < 8) {                          // ---- Tb[b][o]
        int o = tid;
        float c30 = comp[6], c31 = comp[7];
        float acc = 0.f;
        #pragma unroll 4
        for (int k = 0; k < D; ++k)
            acc += tot[k] * (c30 * basis[k * D + o] + c31 * basis[DSQ + k * D + o]);
        Tb[b * D + o] = bias[o] + acc * INV3;
    } else {                              // ---- boundary rows
        int rr = r - 8;
        const int tl[4] = {0, S - 3, S - 2, S - 1};
        int t = tl[rr & 3];
        __shared__ float z0[D], z1[D], xr[D];
        const float* xb = x + (size_t)b * S * D;
        int i = tid;
        float x_t = xb[(size_t)t * D + i];
        float v0 = (t + 1 < S) ? xb[(size_t)(t + 1) * D + i] : 0.f;
        float d1 = 1.f + ((t + 2 < S) ? 1.f : 0.f);
        float v1 = (x_t + ((t + 2 < S) ? xb[(size_t)(t + 2) * D + i] : 0.f)) / d1;
        float s2 = ((t - 1 >= 0) ? xb[(size_t)(t - 1) * D + i] : 0.f)
                 + ((t + 3 < S) ? xb[(size_t)(t + 3) * D + i] : 0.f);
        int d2i = ((t - 1 >= 0) ? 1 : 0) + ((t + 3 < S) ? 1 : 0);
        float v2 = d2i ? s2 / (float)d2i : 0.f;
        float wsum = 0.f;
        for (int s = t - 1; s <= t + 3; ++s)
            if (s >= 0 && s < S) wsum += xb[(size_t)s * D + i];
        int d3i = ((t - 1 > 0) ? (t - 1) : 0) + ((S - 4 - t > 0) ? (S - 4 - t) : 0);
        float v3 = d3i ? (tot[i] - wsum) / (float)d3i : 0.f;
        z0[i] = comp[0] * v0 + comp[2] * v1 + comp[4] * v2 + comp[6] * v3;
        z1[i] = comp[1] * v0 + comp[3] * v1 + comp[5] * v2 + comp[7] * v3;
        xr[i] = x_t;
        __syncthreads();
        int o = tid;
        float acc = 0.f;
        #pragma unroll 8
        for (int k = 0; k < D; ++k)
            acc += z0[k] * basis[k * D + o] + z1[k] * basis[DSQ + k * D + o]
                 + xr[k] * root[k * D + o];
        out[(((size_t)b * S + t) << 8) + o] = acc + bias[o];
    }
}

// ---------------- K2: MFMA bulk GEMM (identical to R7) ---------------------
// Block = 128(m) x 128(n), 256 thr = 4 waves. Grid 128x2, 1 block/CU.
// A: x-tile (132 bf16 rows) staged once via global_load_lds, swizzled.
// B: global->VGPR, prefetch distance 3. A-frags prefetched 1 step ahead.
// NO barriers in the K-loop.
__global__ __launch_bounds__(256) void k_bulk(
        const unsigned short* __restrict__ xh,   // padded rows: [1 + B*S + 3]
        const unsigned short* __restrict__ Cbs,  // [40][256][32]
        const float* __restrict__ Tb,
        float* __restrict__ out) {
    __shared__ __align__(16) unsigned short xs[132 * 256];    // 67584 B
    const int tid  = threadIdx.x;
    const int lane = tid & 63;
    const int w    = tid >> 6;
    const int wm   = w & 1;
    const int wn   = w >> 1;
    const int mblk = blockIdx.x;        // 0..127
    const int nblk = blockIdx.y;        // 0..1
    const int b  = mblk >> 4;
    const int t0 = (mblk & 15) << 7;
    const size_t rowbase = (size_t)b * S + t0;

    #pragma unroll
    for (int q = 0; q < 16; ++q) {
        int F = (q * 256 + tid) * 16;
        int r = F >> 9;
        int c16 = (F >> 4) & 31;
        int gc = (c16 & 24) | ((c16 ^ r) & 7);
        gl2lds16((const char*)xh + ((rowbase + r) << 9) + (gc << 4), (char*)xs + F);
    }
    if (tid < 128) {
        int F = (4096 + tid) * 16;
        int r = F >> 9;
        int c16 = (F >> 4) & 31;
        int gc = (c16 & 24) | ((c16 ^ r) & 7);
        gl2lds16((const char*)xh + ((rowbase + r) << 9) + (gc << 4), (char*)xs + F);
    }
    __syncthreads();

    const int rlo = lane & 15, q4 = lane >> 4;
    const int nstrip = nblk * 128 + wn * 64;
    const int mbase  = wm * 64;

    #define BFRAG(st, nt) (*(const bf16x8*)(Cbs + \
        (((size_t)(st) * 256 + nstrip + (nt) * 16 + rlo) << 5) + (q4 << 3)))
    #define AFRAG(st, mt) (*(const bf16x8*)((const char*)xs + \
        (((mbase + (mt) * 16 + rlo + ((st) >> 3))) << 9) + \
        (((((st) & 7) * 4 + q4) & 24 | ((((st) & 7) * 4 + q4) ^ \
          (mbase + (mt) * 16 + rlo + ((st) >> 3))) & 7) << 4)))

    f32x4 acc[4][4] = {};
    bf16x8 bb[4][4];
    bf16x8 aa[2][4];
    #pragma unroll
    for (int nt = 0; nt < 4; ++nt) {
        bb[0][nt] = BFRAG(0, nt); bb[1][nt] = BFRAG(1, nt); bb[2][nt] = BFRAG(2, nt);
    }
    #pragma unroll
    for (int mt = 0; mt < 4; ++mt) aa[0][mt] = AFRAG(0, mt);

    #pragma unroll
    for (int step = 0; step < 40; ++step) {
        const int pfB = (step + 3 < 40) ? step + 3 : 39;
        #pragma unroll
        for (int nt = 0; nt < 4; ++nt) bb[(step + 3) & 3][nt] = BFRAG(pfB, nt);
        const int pfA = (step + 1 < 40) ? step + 1 : 39;
        #pragma unroll
        for (int mt = 0; mt < 4; ++mt) aa[(step + 1) & 1][mt] = AFRAG(pfA, mt);

        #pragma unroll
        for (int mt = 0; mt < 4; ++mt)
            #pragma unroll
            for (int nt = 0; nt < 4; ++nt)
                acc[mt][nt] = __builtin_amdgcn_mfma_f32_16x16x32_bf16(
                    aa[step & 1][mt], bb[step & 3][nt], acc[mt][nt], 0, 0, 0);
    }
    #undef BFRAG
    #undef AFRAG

    const int col = lane & 15, rq = (lane >> 4) << 2;
    #pragma unroll
    for (int nt = 0; nt < 4; ++nt) {
        int n = nstrip + nt * 16 + col;
        float tb = Tb[b * D + n];
        #pragma unroll
        for (int mt = 0; mt < 4; ++mt) {
            #pragma unroll
            for (int i = 0; i < 4; ++i) {
                int t = t0 + mbase + mt * 16 + rq + i;
                if (t >= 1 && t <= S - 4)
                    out[(((size_t)b * S + t) << 8) + n] = acc[mt][nt][i] + tb;
            }
        }
    }
}

// ---------------- launch ----------------

extern "C" void kernel_launch(void* const* d_in, const int* in_sizes, int n_in,
                              void* d_out, int out_size, void* d_ws, size_t ws_size,
                              hipStream_t stream) {
    const float* x     = (const float*)d_in[0];
    const float* comp  = (const float*)d_in[1];
    const float* basis = (const float*)d_in[2];
    const float* root  = (const float*)d_in[3];
    const float* bias  = (const float*)d_in[4];
    float* out = (float*)d_out;

    char* ws = (char*)d_ws;
    float* total         = (float*)(ws);                    // 8 KB
    unsigned int* flags  = (unsigned int*)(ws + 8192);      // 2 KB
    float* Tb            = (float*)(ws + 12288);            // 8 KB
    unsigned short* Cbs  = (unsigned short*)(ws + 20480);   // 640 KB
    unsigned short* xh   = (unsigned short*)(ws + 1179648); // 16392 rows * 512 B

    k_prep<<<552, 256, 0, stream>>>(x, comp, basis, root, bias,
                                    xh, total, flags, Cbs, Tb, out);
    k_bulk<<<dim3(128, 2), 256, 0, stream>>>(xh, Cbs, Tb, out);
}

// Round 11
// 114.281 us; speedup vs baseline: 1.2268x; 1.2268x over previous
//
#include <hip/hip_runtime.h>

#define D 256
#define S 2048
#define B 8
#define DSQ (D * D)   // 65536
#define INV3 (1.0f / 2043.0f)   // 1/(S-5)

typedef __bf16 bf16x8 __attribute__((ext_vector_type(8)));
typedef float f32x4 __attribute__((ext_vector_type(4)));

__device__ __forceinline__ unsigned short f2bf(float f) {
    union { float f; unsigned int u; } v; v.f = f;
    unsigned int u = v.u;
    u += 0x7fffu + ((u >> 16) & 1u);   // RTNE
    return (unsigned short)(u >> 16);
}

__device__ __forceinline__ void gl2lds16(const void* g, void* l) {
    __builtin_amdgcn_global_load_lds(
        (const __attribute__((address_space(1))) void*)g,
        (__attribute__((address_space(3))) void*)l, 16, 0, 0);
}

// ---------------- K1: bf16 cast + partial sums + Cbs build -----------------
// 512 blocks x 256 thr; block = 32 rows of one b. x is HBM-cold here (L3
// flushed by the harness ws-poison) — the one full-BW pass over x.
__global__ __launch_bounds__(256) void k_prep(const float* __restrict__ x,
                                              const float* __restrict__ comp,
                                              const float* __restrict__ basis,
                                              const float* __restrict__ root,
                                              unsigned short* __restrict__ xh,
                                              float* __restrict__ part,
                                              unsigned short* __restrict__ Cbs) {
    int blk = blockIdx.x;            // b*64 + chunk
    int tid = threadIdx.x;
    int b = blk >> 6, chunk = blk & 63;
    __shared__ float ps[4][D];
    int rg = tid >> 6;               // 0..3 row-group (8 rows each)
    int c4 = (tid & 63) << 2;
    int row0 = chunk * 32 + rg * 8;
    const float4* xb = (const float4*)(x + ((size_t)b * S + row0) * D + c4);
    ushort4* dst = (ushort4*)(xh + ((size_t)(1 + b * S + row0)) * D + c4);
    float4 s = {0.f, 0.f, 0.f, 0.f};
    #pragma unroll
    for (int i = 0; i < 8; ++i) {
        float4 v = xb[(size_t)i * 64];
        ushort4 o;
        o.x = f2bf(v.x); o.y = f2bf(v.y); o.z = f2bf(v.z); o.w = f2bf(v.w);
        dst[(size_t)i * 64] = o;
        s.x += v.x; s.y += v.y; s.z += v.z; s.w += v.w;
    }
    *(float4*)&ps[rg][c4] = s;

    if (blk < 160) {                 // Cbs[step][n][32] bf16 (independent of x)
        int step = blk >> 2, q = blk & 3;
        int ji = step >> 3, kc = step & 7;
        int n = tid;
        float a0 = (ji == 2) ? 1.f : 0.f;
        float a1 = (ji == 1 || ji == 3) ? 0.5f : 0.f;
        float a2 = (ji == 0 || ji == 4) ? 0.5f : 0.f;
        float ar = (ji == 1) ? 1.f : 0.f;
        float cb0 = a0 * comp[0] + a1 * comp[2] + a2 * comp[4] - INV3 * comp[6];
        float cb1 = a0 * comp[1] + a1 * comp[3] + a2 * comp[5] - INV3 * comp[7];
        unsigned short buf[8];
        #pragma unroll
        for (int kk = 0; kk < 8; ++kk) {
            int i = kc * 32 + q * 8 + kk;
            buf[kk] = f2bf(cb0 * basis[i * D + n] + cb1 * basis[DSQ + i * D + n]
                           + ar * root[i * D + n]);
        }
        *(uint4*)(Cbs + ((size_t)step * 256 + n) * 32 + q * 8) = *(uint4*)buf;
    }
    __syncthreads();
    if (tid < 64)
        *(float4*)&part[(size_t)blk * D + tid * 4] =
            *(float4*)&ps[0][tid * 4] + *(float4*)&ps[1][tid * 4] +
            *(float4*)&ps[2][tid * 4] + *(float4*)&ps[3][tid * 4];
}

// ---------------- K2: Tb + boundary rows (40 blocks) -----------------------
__global__ __launch_bounds__(256) void k_weights(
        const float* __restrict__ basis, const float* __restrict__ comp,
        const float* __restrict__ root, const float* __restrict__ bias,
        const float* __restrict__ part, const float* __restrict__ x,
        float* __restrict__ Tb, float* __restrict__ out) {
    int blk = blockIdx.x;
    int tid = threadIdx.x;

    if (blk < 8) {                           // ---- Tb[b][o], single writer
        int b = blk;
        __shared__ float tot[D];
        float t = 0.f;
        #pragma unroll 8
        for (int c = 0; c < 64; ++c) t += part[(size_t)(b * 64 + c) * D + tid];
        tot[tid] = t;
        __syncthreads();
        int o = tid;
        float c30 = comp[6], c31 = comp[7];
        float acc = 0.f;
        #pragma unroll 4
        for (int k = 0; k < D; ++k)
            acc += tot[k] * (c30 * basis[k * D + o] + c31 * basis[DSQ + k * D + o]);
        Tb[b * D + o] = bias[o] + acc * INV3;
    } else {                                 // ---- boundary rows
        int r = blk - 8;
        const int tl[4] = {0, S - 3, S - 2, S - 1};
        int t = tl[r & 3], b = r >> 2;
        __shared__ float z0[D], z1[D], xr[D];
        const float* xb = x + (size_t)b * S * D;
        int i = tid;
        float tot = 0.f;
        #pragma unroll 8
        for (int c = 0; c < 64; ++c) tot += part[(size_t)(b * 64 + c) * D + i];
        float x_t = xb[(size_t)t * D + i];
        float v0 = (t + 1 < S) ? xb[(size_t)(t + 1) * D + i] : 0.f;
        float d1 = 1.f + ((t + 2 < S) ? 1.f : 0.f);
        float v1 = (x_t + ((t + 2 < S) ? xb[(size_t)(t + 2) * D + i] : 0.f)) / d1;
        float s2 = ((t - 1 >= 0) ? xb[(size_t)(t - 1) * D + i] : 0.f)
                 + ((t + 3 < S) ? xb[(size_t)(t + 3) * D + i] : 0.f);
        int d2i = ((t - 1 >= 0) ? 1 : 0) + ((t + 3 < S) ? 1 : 0);
        float v2 = d2i ? s2 / (float)d2i : 0.f;
        float wsum = 0.f;
        for (int s = t - 1; s <= t + 3; ++s)
            if (s >= 0 && s < S) wsum += xb[(size_t)s * D + i];
        int d3i = ((t - 1 > 0) ? (t - 1) : 0) + ((S - 4 - t > 0) ? (S - 4 - t) : 0);
        float v3 = d3i ? (tot - wsum) / (float)d3i : 0.f;
        z0[i] = comp[0] * v0 + comp[2] * v1 + comp[4] * v2 + comp[6] * v3;
        z1[i] = comp[1] * v0 + comp[3] * v1 + comp[5] * v2 + comp[7] * v3;
        xr[i] = x_t;
        __syncthreads();
        int o = tid;
        float acc = 0.f;
        #pragma unroll 8
        for (int k = 0; k < D; ++k)
            acc += z0[k] * basis[k * D + o] + z1[k] * basis[DSQ + k * D + o]
                 + xr[k] * root[k * D + o];
        out[(((size_t)b * S + t) << 8) + o] = acc + bias[o];
    }
}

// ---------------- K3: MFMA bulk GEMM, 2 blocks/CU --------------------------
// Block = 64(m) x 128(n), 256 thr = 4 waves; each wave 64m x 32n
// (4x2 of 16x16x32). Grid 512 blocks -> 2 blocks/CU, 2 waves/SIMD: stalls in
// one block overlap with the other's MFMA. A: 68-row x-tile (34.8 KB) staged
// once via global_load_lds, swizzled. B: global->VGPR, prefetch distance 3.
// A-frags prefetched 1 step ahead. NO barriers in the K-loop.
__global__ __launch_bounds__(256) void k_bulk(
        const unsigned short* __restrict__ xh,   // padded rows: [1 + B*S + 3]
        const unsigned short* __restrict__ Cbs,  // [40][256][32]
        const float* __restrict__ Tb,
        float* __restrict__ out) {
    __shared__ __align__(16) unsigned short xs[68 * 256];     // 34816 B
    const int tid  = threadIdx.x;
    const int lane = tid & 63;
    const int w    = tid >> 6;          // wave -> 32-col n sub-strip
    const int blk  = blockIdx.x;        // 0..511
    const int nblk = blk & 1;
    const int mblk = blk >> 1;          // 0..255
    const int b    = mblk >> 5;
    const int t0   = (mblk & 31) << 6;
    const size_t rowbase = (size_t)b * S + t0;   // padded row of x[b][t0-1]

    // stage x tile: 68 rows x 512B = 2176 16B-chunks, swizzled
    #pragma unroll
    for (int q = 0; q < 8; ++q) {
        int F = (q * 256 + tid) * 16;
        int r = F >> 9;
        int c16 = (F >> 4) & 31;
        int gc = (c16 & 24) | ((c16 ^ r) & 7);
        gl2lds16((const char*)xh + ((rowbase + r) << 9) + (gc << 4), (char*)xs + F);
    }
    if (tid < 128) {
        int F = (2048 + tid) * 16;
        int r = F >> 9;
        int c16 = (F >> 4) & 31;
        int gc = (c16 & 24) | ((c16 ^ r) & 7);
        gl2lds16((const char*)xh + ((rowbase + r) << 9) + (gc << 4), (char*)xs + F);
    }
    __syncthreads();

    const int rlo = lane & 15, q4 = lane >> 4;
    const int nstrip = nblk * 128 + w * 32;

    #define BFRAG(st, nt) (*(const bf16x8*)(Cbs + \
        (((size_t)(st) * 256 + nstrip + (nt) * 16 + rlo) << 5) + (q4 << 3)))
    #define AFRAG(st, mt) (*(const bf16x8*)((const char*)xs + \
        ((((mt) * 16 + rlo + ((st) >> 3))) << 9) + \
        (((((st) & 7) * 4 + q4) & 24 | ((((st) & 7) * 4 + q4) ^ \
          ((mt) * 16 + rlo + ((st) >> 3))) & 7) << 4)))

    f32x4 acc[4][2] = {};
    bf16x8 bb[4][2];
    bf16x8 aa[2][4];
    #pragma unroll
    for (int nt = 0; nt < 2; ++nt) {
        bb[0][nt] = BFRAG(0, nt); bb[1][nt] = BFRAG(1, nt); bb[2][nt] = BFRAG(2, nt);
    }
    #pragma unroll
    for (int mt = 0; mt < 4; ++mt) aa[0][mt] = AFRAG(0, mt);

    #pragma unroll
    for (int step = 0; step < 40; ++step) {
        const int pfB = (step + 3 < 40) ? step + 3 : 39;
        #pragma unroll
        for (int nt = 0; nt < 2; ++nt) bb[(step + 3) & 3][nt] = BFRAG(pfB, nt);
        const int pfA = (step + 1 < 40) ? step + 1 : 39;
        #pragma unroll
        for (int mt = 0; mt < 4; ++mt) aa[(step + 1) & 1][mt] = AFRAG(pfA, mt);

        #pragma unroll
        for (int mt = 0; mt < 4; ++mt)
            #pragma unroll
            for (int nt = 0; nt < 2; ++nt)
                acc[mt][nt] = __builtin_amdgcn_mfma_f32_16x16x32_bf16(
                    aa[step & 1][mt], bb[step & 3][nt], acc[mt][nt], 0, 0, 0);
    }
    #undef BFRAG
    #undef AFRAG

    // epilogue: C/D layout col=lane&15, row=(lane>>4)*4+i
    const int col = lane & 15, rq = (lane >> 4) << 2;
    #pragma unroll
    for (int nt = 0; nt < 2; ++nt) {
        int n = nstrip + nt * 16 + col;
        float tb = Tb[b * D + n];
        #pragma unroll
        for (int mt = 0; mt < 4; ++mt) {
            #pragma unroll
            for (int i = 0; i < 4; ++i) {
                int t = t0 + mt * 16 + rq + i;
                if (t >= 1 && t <= S - 4)
                    out[(((size_t)b * S + t) << 8) + n] = acc[mt][nt][i] + tb;
            }
        }
    }
}

// ---------------- launch ----------------

extern "C" void kernel_launch(void* const* d_in, const int* in_sizes, int n_in,
                              void* d_out, int out_size, void* d_ws, size_t ws_size,
                              hipStream_t stream) {
    const float* x     = (const float*)d_in[0];
    const float* comp  = (const float*)d_in[1];
    const float* basis = (const float*)d_in[2];
    const float* root  = (const float*)d_in[3];
    const float* bias  = (const float*)d_in[4];
    float* out = (float*)d_out;

    // ws layout (NO overlap — R10's bug was xh at 1179648 < Cbs end 1187840):
    // part [0, 524288)  Tb [524288, 532480)  Cbs [532480, 1187840)
    // xh   [1187840, 1187840 + 16392*512)
    char* ws = (char*)d_ws;
    float* part         = (float*)(ws);
    float* Tb           = (float*)(ws + 524288);
    unsigned short* Cbs = (unsigned short*)(ws + 532480);
    unsigned short* xh  = (unsigned short*)(ws + 1187840);

    k_prep   <<<512, 256, 0, stream>>>(x, comp, basis, root, xh, part, Cbs);
    k_weights<<<40,  256, 0, stream>>>(basis, comp, root, bias, part, x, Tb, out);
    k_bulk   <<<512, 256, 0, stream>>>(xh, Cbs, Tb, out);
}